// Round 11
// baseline (224.764 us; speedup 1.0000x reference)
//
#include <hip/hip_runtime.h>
#include <hip/hip_bf16.h>
#include <cstdint>

// Problem dims
#define Bn 8
#define Cn 256
#define Hn 48
#define NUM_MEM 9
#define WSZ 16
#define Sn 128
#define Dn 65536   // 16*16*256
#define KTOP 5
#define NDC 128    // d-chunks (512 floats each)
#define CTH 46     // dc < CTH -> cached; else NT stream

typedef float f32x4 __attribute__((ext_vector_type(4)));

// ---------------- Phase A: x (B,C,H,W) -> q (B,M,D), D = (i*16+j)*256 + c ----
__global__ __launch_bounds__(256) void k_x2q(const float* __restrict__ x,
                                             float* __restrict__ q) {
    const int h = blockIdx.x;          // 0..47
    const int b = blockIdx.y;          // 0..7
    const int gh = h >> 4, i = h & 15;
    __shared__ float tile[Cn * Hn];    // [c][w], 48KB
    const float* xp = x + (size_t)b * Cn * Hn * Hn + (size_t)h * Hn;
    for (int o = threadIdx.x; o < Cn * Hn; o += blockDim.x) {
        int c = o / Hn, w = o - c * Hn;
        tile[o] = xp[(size_t)c * Hn * Hn + w];
    }
    __syncthreads();
    for (int gw = 0; gw < 3; ++gw) {
        float* qp = q + (size_t)(b * NUM_MEM + gh * 3 + gw) * Dn + i * (WSZ * Cn);
        for (int l = threadIdx.x; l < WSZ * Cn; l += blockDim.x) {
            int j = l >> 8, c = l & 255;
            qp[l] = tile[c * Hn + gw * WSZ + j];
        }
    }
}

// ---------------- Phase B: 16-wave single-shot partial dots ------------------
// Dispatch-rate fix: same per-wave workload as the round-10 winner (4 rows x
// 2KB NT/cached split + 8-batch q), but 16 waves per block (4 dc-chunks x 4
// row-quads) -> 4608 WGs at 128KB mem each instead of 18432 at 32KB. If the
// ~130 WG/us dispatch rate was the service cap (rate x 32KB = 4.2 TB/s, the
// ceiling every prior design hit), quadrupling bytes/WG lifts it.
// ap[dc][(e*8+b)*9+m][s] = partial dot over the 512-float chunk.
__global__ __launch_bounds__(1024) void k_att10(const float* __restrict__ q,
                                                const float* __restrict__ mem1,
                                                const float* __restrict__ mem2,
                                                float* __restrict__ ap) {
    const int dcq = blockIdx.x;    // 0..31
    const int mw  = blockIdx.y;    // 0..8
    const int sg  = blockIdx.z;    // 0..15
    const int e   = sg >> 3;
    const int wv   = threadIdx.x >> 6;   // 0..15
    const int lane = threadIdx.x & 63;
    const int dc = dcq * 4 + (wv >> 2);             // 0..127
    const int s0 = (sg & 7) * 16 + (wv & 3) * 4;    // first of 4 s-rows

    const f32x4* mem4 = (const f32x4*)(e ? mem2 : mem1);
    const f32x4* q4   = (const f32x4*)q;
    const int off = dc * 128 + lane;                // f32x4 offset of slice 0

    // 8 independent mem loads (4 rows x 2 slices), issued up-front.
    f32x4 M[4][2];
    if (dc < CTH) {
#pragma unroll
        for (int r = 0; r < 4; ++r) {
            const f32x4* mp = mem4 + (size_t)(mw * Sn + s0 + r) * (Dn / 4) + off;
            M[r][0] = mp[0];
            M[r][1] = mp[64];
        }
    } else {
#pragma unroll
        for (int r = 0; r < 4; ++r) {
            const f32x4* mp = mem4 + (size_t)(mw * Sn + s0 + r) * (Dn / 4) + off;
            M[r][0] = __builtin_nontemporal_load(mp);
            M[r][1] = __builtin_nontemporal_load(mp + 64);
        }
    }

    float a[32];                                    // a[r*8+b]
#pragma unroll
    for (int i = 0; i < 32; ++i) a[i] = 0.f;

    // q in two b-halves to cap register pressure (q always cached: real reuse)
#pragma unroll
    for (int half = 0; half < 2; ++half) {
        f32x4 Q[4][2];
#pragma unroll
        for (int b = 0; b < 4; ++b) {
            const f32x4* qp = q4 + (size_t)((half * 4 + b) * NUM_MEM + mw) * (Dn / 4) + off;
            Q[b][0] = qp[0];
            Q[b][1] = qp[64];
        }
#pragma unroll
        for (int r = 0; r < 4; ++r)
#pragma unroll
            for (int b = 0; b < 4; ++b) {
                const int bi = half * 4 + b;
                float acc = a[r * 8 + bi];
#pragma unroll
                for (int k = 0; k < 4; ++k)
                    acc += M[r][0][k] * Q[b][0][k] + M[r][1][k] * Q[b][1][k];
                a[r * 8 + bi] = acc;
            }
    }

    // fold-reduce: 32 values across 64 lanes (verified rounds 3-10)
#pragma unroll
    for (int k = 0; k < 5; ++k) {
        const int mk = 1 << k;
        const bool up = (lane & mk) != 0;
#pragma unroll
        for (int j = 0; j < (32 >> (k + 1)); ++j) {
            float lo = a[2 * j], hi = a[2 * j + 1];
            float mine = up ? hi : lo;
            float oth  = __shfl_xor(up ? lo : hi, mk, 64);
            a[j] = mine + oth;
        }
    }
    float rsum = a[0] + __shfl_xor(a[0], 32, 64);
    if (lane < 32) {
        const int b = lane & 7, r = (lane >> 3) & 3;
        ap[((size_t)dc * 144 + (size_t)(e * 8 + b) * 9 + mw) * Sn + (s0 + r)] = rsum;
    }
}

// ---------------- Phase C: nd-reduce + softmax + top-5 + shrink + L1 --------
__global__ __launch_bounds__(128) void k_smax(const float* __restrict__ ap,
                                              float* __restrict__ w) {
    const int row = blockIdx.x;        // 0..143  = (e*8+b)*9+m
    const int t = threadIdx.x;         // 0..127
    __shared__ float sf[Sn];
    __shared__ unsigned long long sk[Sn];

    float v = 0.f;
#pragma unroll 8
    for (int nd = 0; nd < NDC; ++nd)
        v += ap[((size_t)nd * 144 + row) * Sn + t];

    sf[t] = v; __syncthreads();
    for (int s = 64; s > 0; s >>= 1) { if (t < s) sf[t] = fmaxf(sf[t], sf[t + s]); __syncthreads(); }
    float mx = sf[0]; __syncthreads();

    float e = expf(v - mx);
    sf[t] = e; __syncthreads();
    for (int s = 64; s > 0; s >>= 1) { if (t < s) sf[t] += sf[t + s]; __syncthreads(); }
    float sum = sf[0]; __syncthreads();
    float y = e / sum;                 // softmax (y > 0)

    // 5 iterations of packed (value,index) argmax-with-exclusion -> 5th largest
    bool alive = true;
    float thres = 0.f;
    unsigned int ybits = __float_as_uint(y);   // y>0 -> bits monotonic
    for (int it = 0; it < KTOP; ++it) {
        sk[t] = alive ? ((((unsigned long long)ybits) << 32) | (unsigned)t) : 0ull;
        __syncthreads();
        for (int s = 64; s > 0; s >>= 1) {
            if (t < s) { if (sk[t + s] > sk[t]) sk[t] = sk[t + s]; }
            __syncthreads();
        }
        unsigned long long kmax = sk[0];
        __syncthreads();
        if ((unsigned)(kmax & 0xffffffffull) == (unsigned)t) alive = false;
        thres = __uint_as_float((unsigned)(kmax >> 32));
    }

    float d   = y - thres;
    float num = fmaxf(d, 0.f) * y;
    float yh  = num / (fabsf(d) + 1e-12f);     // exact reference formula

    sf[t] = yh; __syncthreads();
    for (int s = 64; s > 0; s >>= 1) { if (t < s) sf[t] += sf[t + s]; __syncthreads(); }
    float l1 = sf[0];
    w[(size_t)row * Sn + t] = yh / fmaxf(l1, 1e-12f);
}

// ---------------- Phase D+E fused: sparse accumulate -> direct out write ----
__global__ __launch_bounds__(256) void k_accout(const float* __restrict__ w,
                                                const float* __restrict__ mem1,
                                                const float* __restrict__ mem2,
                                                float* __restrict__ out) {
    const int chunk = blockIdx.x;      // 0..15  == i
    const int m     = blockIdx.y;      // 0..8
    const int b     = blockIdx.z;      // 0..7
    const int gh = m / 3, gw = m % 3;
    __shared__ int   nz[2];
    __shared__ int   idx[2][16];
    __shared__ float wv[2][16];
    __shared__ float lds[16 * 257];    // [j][c], padded
    if (threadIdx.x < 2) nz[threadIdx.x] = 0;
    __syncthreads();
    {
        int eidx = threadIdx.x >> 7;           // 0 or 1
        int s    = threadIdx.x & 127;
        float ww = w[((size_t)(eidx * Bn + b) * NUM_MEM + m) * Sn + s];
        if (ww != 0.f) {
            int p = atomicAdd(&nz[eidx], 1);
            if (p < 16) { idx[eidx][p] = s; wv[eidx][p] = ww; }
        }
    }
    __syncthreads();
    const int n1 = nz[0], n2 = nz[1];
    const size_t mbase = (size_t)m * Sn * Dn;
    const int dbase = chunk * 4096;
    const bool temporal = (chunk < 6);
    for (int l = threadIdx.x * 4; l < 4096; l += 1024) {
        int d = dbase + l;
        float4 a = {0.f, 0.f, 0.f, 0.f};
        if (temporal) {
            for (int j = 0; j < n1; ++j) {
                const f32x4 r = *(const f32x4*)(mem1 + mbase + (size_t)idx[0][j] * Dn + d);
                float ww = wv[0][j];
                a.x += ww * r.x; a.y += ww * r.y; a.z += ww * r.z; a.w += ww * r.w;
            }
            for (int j = 0; j < n2; ++j) {
                const f32x4 r = *(const f32x4*)(mem2 + mbase + (size_t)idx[1][j] * Dn + d);
                float ww = wv[1][j];
                a.x += ww * r.x; a.y += ww * r.y; a.z += ww * r.z; a.w += ww * r.w;
            }
        } else {
            for (int j = 0; j < n1; ++j) {
                const f32x4 r = __builtin_nontemporal_load(
                    (const f32x4*)(mem1 + mbase + (size_t)idx[0][j] * Dn + d));
                float ww = wv[0][j];
                a.x += ww * r.x; a.y += ww * r.y; a.z += ww * r.z; a.w += ww * r.w;
            }
            for (int j = 0; j < n2; ++j) {
                const f32x4 r = __builtin_nontemporal_load(
                    (const f32x4*)(mem2 + mbase + (size_t)idx[1][j] * Dn + d));
                float ww = wv[1][j];
                a.x += ww * r.x; a.y += ww * r.y; a.z += ww * r.z; a.w += ww * r.w;
            }
        }
        const int jj = l >> 8, cc = l & 255;   // 4 consecutive c, fixed j
        float* lp = &lds[jj * 257 + cc];
        lp[0] = a.x; lp[1] = a.y; lp[2] = a.z; lp[3] = a.w;
    }
    __syncthreads();
    const int row = gh * WSZ + chunk;
    float* op = out + (size_t)b * Cn * Hn * Hn + (size_t)row * Hn + gw * WSZ;
    for (int o = threadIdx.x; o < 4096; o += 256) {
        const int c = o >> 4, j = o & 15;
        op[(size_t)c * Hn * Hn + j] = lds[j * 257 + c];
    }
}

extern "C" void kernel_launch(void* const* d_in, const int* in_sizes, int n_in,
                              void* d_out, int out_size, void* d_ws, size_t ws_size,
                              hipStream_t stream) {
    const float* x    = (const float*)d_in[0];
    const float* mem1 = (const float*)d_in[1];
    const float* mem2 = (const float*)d_in[2];
    float* out = (float*)d_out;

    // workspace: q [B*M*D floats], w [2*B*M*S floats]
    float* q    = (float*)d_ws;
    float* wbuf = q + (size_t)Bn * NUM_MEM * Dn;
    // att partials live in d_out (9.4 MB of its 18.9 MB) — k_accout overwrites all later
    float* ap   = (float*)d_out;

    k_x2q<<<dim3(Hn, Bn), 256, 0, stream>>>(x, q);
    k_att10<<<dim3(32, NUM_MEM, 16), 1024, 0, stream>>>(q, mem1, mem2, ap);
    k_smax<<<2 * Bn * NUM_MEM, 128, 0, stream>>>(ap, wbuf);
    k_accout<<<dim3(16, NUM_MEM, Bn), 256, 0, stream>>>(wbuf, mem1, mem2, out);
}

// Round 12
// 187.505 us; speedup vs baseline: 1.1987x; 1.1987x over previous
//
#include <hip/hip_runtime.h>
#include <hip/hip_bf16.h>
#include <cstdint>

// Problem dims
#define Bn 8
#define Cn 256
#define Hn 48
#define NUM_MEM 9
#define WSZ 16
#define Sn 128
#define Dn 65536   // 16*16*256
#define KTOP 5
#define NDC 128    // d-chunks (512 floats each)
#define CTH 46     // dc < CTH -> cached; else NT stream

typedef float f32x4 __attribute__((ext_vector_type(4)));

// ---------------- Phase A: x (B,C,H,W) -> q (B,M,D), D = (i*16+j)*256 + c ----
__global__ __launch_bounds__(256) void k_x2q(const float* __restrict__ x,
                                             float* __restrict__ q) {
    const int h = blockIdx.x;          // 0..47
    const int b = blockIdx.y;          // 0..7
    const int gh = h >> 4, i = h & 15;
    __shared__ float tile[Cn * Hn];    // [c][w], 48KB
    const float* xp = x + (size_t)b * Cn * Hn * Hn + (size_t)h * Hn;
    for (int o = threadIdx.x; o < Cn * Hn; o += blockDim.x) {
        int c = o / Hn, w = o - c * Hn;
        tile[o] = xp[(size_t)c * Hn * Hn + w];
    }
    __syncthreads();
    for (int gw = 0; gw < 3; ++gw) {
        float* qp = q + (size_t)(b * NUM_MEM + gh * 3 + gw) * Dn + i * (WSZ * Cn);
        for (int l = threadIdx.x; l < WSZ * Cn; l += blockDim.x) {
            int j = l >> 8, c = l & 255;
            qp[l] = tile[c * Hn + gw * WSZ + j];
        }
    }
}

// ---------------- Phase B: single-shot partial dots, SPLIT temporal/NT ------
// Round-10 winner verbatim (best measured: 190.9 us total).
// ap[dc][(e*8+b)*9+m][s] = partial dot over the 512-float chunk.
__global__ __launch_bounds__(256) void k_att8(const float* __restrict__ q,
                                              const float* __restrict__ mem1,
                                              const float* __restrict__ mem2,
                                              float* __restrict__ ap) {
    const int dc = blockIdx.x;     // 0..127
    const int mw = blockIdx.y;     // 0..8
    const int sg = blockIdx.z;     // 0..15
    const int e  = sg >> 3;
    const int lane = threadIdx.x & 63, wave = threadIdx.x >> 6;
    const int s0 = (sg & 7) * 16 + wave * 4;        // first of 4 s-rows

    const f32x4* mem4 = (const f32x4*)(e ? mem2 : mem1);
    const f32x4* q4   = (const f32x4*)q;
    const int off = dc * 128 + lane;                // f32x4 offset of slice 0

    f32x4 M[4][2];
    if (dc < CTH) {
#pragma unroll
        for (int r = 0; r < 4; ++r) {
            const f32x4* mp = mem4 + (size_t)(mw * Sn + s0 + r) * (Dn / 4) + off;
            M[r][0] = mp[0];
            M[r][1] = mp[64];
        }
    } else {
#pragma unroll
        for (int r = 0; r < 4; ++r) {
            const f32x4* mp = mem4 + (size_t)(mw * Sn + s0 + r) * (Dn / 4) + off;
            M[r][0] = __builtin_nontemporal_load(mp);
            M[r][1] = __builtin_nontemporal_load(mp + 64);
        }
    }

    float a[32];                                    // a[r*8+b]
#pragma unroll
    for (int i = 0; i < 32; ++i) a[i] = 0.f;

#pragma unroll
    for (int half = 0; half < 2; ++half) {
        f32x4 Q[4][2];
#pragma unroll
        for (int b = 0; b < 4; ++b) {
            const f32x4* qp = q4 + (size_t)((half * 4 + b) * NUM_MEM + mw) * (Dn / 4) + off;
            Q[b][0] = qp[0];
            Q[b][1] = qp[64];
        }
#pragma unroll
        for (int r = 0; r < 4; ++r)
#pragma unroll
            for (int b = 0; b < 4; ++b) {
                const int bi = half * 4 + b;
                float acc = a[r * 8 + bi];
#pragma unroll
                for (int k = 0; k < 4; ++k)
                    acc += M[r][0][k] * Q[b][0][k] + M[r][1][k] * Q[b][1][k];
                a[r * 8 + bi] = acc;
            }
    }

    // fold-reduce: 32 values across 64 lanes (verified rounds 3-11)
#pragma unroll
    for (int k = 0; k < 5; ++k) {
        const int mk = 1 << k;
        const bool up = (lane & mk) != 0;
#pragma unroll
        for (int j = 0; j < (32 >> (k + 1)); ++j) {
            float lo = a[2 * j], hi = a[2 * j + 1];
            float mine = up ? hi : lo;
            float oth  = __shfl_xor(up ? lo : hi, mk, 64);
            a[j] = mine + oth;
        }
    }
    float rsum = a[0] + __shfl_xor(a[0], 32, 64);
    if (lane < 32) {
        const int b = lane & 7, r = (lane >> 3) & 3;
        ap[((size_t)dc * 144 + (size_t)(e * 8 + b) * 9 + mw) * Sn + (s0 + r)] = rsum;
    }
}

// ---------------- Phase C: nd-reduce + softmax + top-5 + shrink + L1 --------
__global__ __launch_bounds__(128) void k_smax(const float* __restrict__ ap,
                                              float* __restrict__ w) {
    const int row = blockIdx.x;        // 0..143  = (e*8+b)*9+m
    const int t = threadIdx.x;         // 0..127
    __shared__ float sf[Sn];
    __shared__ unsigned long long sk[Sn];

    float v = 0.f;
#pragma unroll 8
    for (int nd = 0; nd < NDC; ++nd)
        v += ap[((size_t)nd * 144 + row) * Sn + t];

    sf[t] = v; __syncthreads();
    for (int s = 64; s > 0; s >>= 1) { if (t < s) sf[t] = fmaxf(sf[t], sf[t + s]); __syncthreads(); }
    float mx = sf[0]; __syncthreads();

    float e = expf(v - mx);
    sf[t] = e; __syncthreads();
    for (int s = 64; s > 0; s >>= 1) { if (t < s) sf[t] += sf[t + s]; __syncthreads(); }
    float sum = sf[0]; __syncthreads();
    float y = e / sum;                 // softmax (y > 0)

    // 5 iterations of packed (value,index) argmax-with-exclusion -> 5th largest
    bool alive = true;
    float thres = 0.f;
    unsigned int ybits = __float_as_uint(y);   // y>0 -> bits monotonic
    for (int it = 0; it < KTOP; ++it) {
        sk[t] = alive ? ((((unsigned long long)ybits) << 32) | (unsigned)t) : 0ull;
        __syncthreads();
        for (int s = 64; s > 0; s >>= 1) {
            if (t < s) { if (sk[t + s] > sk[t]) sk[t] = sk[t + s]; }
            __syncthreads();
        }
        unsigned long long kmax = sk[0];
        __syncthreads();
        if ((unsigned)(kmax & 0xffffffffull) == (unsigned)t) alive = false;
        thres = __uint_as_float((unsigned)(kmax >> 32));
    }

    float d   = y - thres;
    float num = fmaxf(d, 0.f) * y;
    float yh  = num / (fabsf(d) + 1e-12f);     // exact reference formula

    sf[t] = yh; __syncthreads();
    for (int s = 64; s > 0; s >>= 1) { if (t < s) sf[t] += sf[t + s]; __syncthreads(); }
    float l1 = sf[0];
    w[(size_t)row * Sn + t] = yh / fmaxf(l1, 1e-12f);
}

// ---------------- Phase D+E fused: sparse accumulate -> direct out write ----
// One change vs round 10: ALL reads cached (no NT). k_att8 leaves ~40% of mem
// L3-resident within this replay; NT was bypassing those hits.
__global__ __launch_bounds__(256) void k_accout(const float* __restrict__ w,
                                                const float* __restrict__ mem1,
                                                const float* __restrict__ mem2,
                                                float* __restrict__ out) {
    const int chunk = blockIdx.x;      // 0..15  == i
    const int m     = blockIdx.y;      // 0..8
    const int b     = blockIdx.z;      // 0..7
    const int gh = m / 3, gw = m % 3;
    __shared__ int   nz[2];
    __shared__ int   idx[2][16];
    __shared__ float wv[2][16];
    __shared__ float lds[16 * 257];    // [j][c], padded
    if (threadIdx.x < 2) nz[threadIdx.x] = 0;
    __syncthreads();
    {
        int eidx = threadIdx.x >> 7;           // 0 or 1
        int s    = threadIdx.x & 127;
        float ww = w[((size_t)(eidx * Bn + b) * NUM_MEM + m) * Sn + s];
        if (ww != 0.f) {
            int p = atomicAdd(&nz[eidx], 1);
            if (p < 16) { idx[eidx][p] = s; wv[eidx][p] = ww; }
        }
    }
    __syncthreads();
    const int n1 = nz[0], n2 = nz[1];
    const size_t mbase = (size_t)m * Sn * Dn;
    const int dbase = chunk * 4096;
    for (int l = threadIdx.x * 4; l < 4096; l += 1024) {
        int d = dbase + l;
        float4 a = {0.f, 0.f, 0.f, 0.f};
        for (int j = 0; j < n1; ++j) {
            const f32x4 r = *(const f32x4*)(mem1 + mbase + (size_t)idx[0][j] * Dn + d);
            float ww = wv[0][j];
            a.x += ww * r.x; a.y += ww * r.y; a.z += ww * r.z; a.w += ww * r.w;
        }
        for (int j = 0; j < n2; ++j) {
            const f32x4 r = *(const f32x4*)(mem2 + mbase + (size_t)idx[1][j] * Dn + d);
            float ww = wv[1][j];
            a.x += ww * r.x; a.y += ww * r.y; a.z += ww * r.z; a.w += ww * r.w;
        }
        const int jj = l >> 8, cc = l & 255;   // 4 consecutive c, fixed j
        float* lp = &lds[jj * 257 + cc];
        lp[0] = a.x; lp[1] = a.y; lp[2] = a.z; lp[3] = a.w;
    }
    __syncthreads();
    const int row = gh * WSZ + chunk;
    float* op = out + (size_t)b * Cn * Hn * Hn + (size_t)row * Hn + gw * WSZ;
    for (int o = threadIdx.x; o < 4096; o += 256) {
        const int c = o >> 4, j = o & 15;
        op[(size_t)c * Hn * Hn + j] = lds[j * 257 + c];
    }
}

extern "C" void kernel_launch(void* const* d_in, const int* in_sizes, int n_in,
                              void* d_out, int out_size, void* d_ws, size_t ws_size,
                              hipStream_t stream) {
    const float* x    = (const float*)d_in[0];
    const float* mem1 = (const float*)d_in[1];
    const float* mem2 = (const float*)d_in[2];
    float* out = (float*)d_out;

    // workspace: q [B*M*D floats], w [2*B*M*S floats]
    float* q    = (float*)d_ws;
    float* wbuf = q + (size_t)Bn * NUM_MEM * Dn;
    // att partials live in d_out (9.4 MB of its 18.9 MB) — k_accout overwrites all later
    float* ap   = (float*)d_out;

    k_x2q<<<dim3(Hn, Bn), 256, 0, stream>>>(x, q);
    k_att8<<<dim3(NDC, NUM_MEM, 16), 256, 0, stream>>>(q, mem1, mem2, ap);
    k_smax<<<2 * Bn * NUM_MEM, 128, 0, stream>>>(ap, wbuf);
    k_accout<<<dim3(16, NUM_MEM, Bn), 256, 0, stream>>>(wbuf, mem1, mem2, out);
}